// Round 3
// baseline (889.691 us; speedup 1.0000x reference)
//
#include <hip/hip_runtime.h>

#define N_INST 100
#define HW_PIX 819200
#define NPAIR (N_INST * N_INST)

// K0: argsort(cls_prob) descending, tie-break larger original index first
// (== jnp stable-ascending argsort reversed).
__global__ __launch_bounds__(128) void k0_sort(
    const float* __restrict__ cls_prob,
    const int* __restrict__ cls_idx,
    int* __restrict__ order,
    int* __restrict__ cls_sorted,
    float* __restrict__ out_order) {
  __shared__ float v[N_INST];
  __shared__ int ordl[N_INST];
  int t = threadIdx.x;
  if (t < N_INST) v[t] = cls_prob[t];
  __syncthreads();
  if (t < N_INST) {
    float mv = v[t];
    int r = 0;
    for (int j = 0; j < N_INST; ++j) {
      float vj = v[j];
      r += (vj > mv) || (vj == mv && j > t);
    }
    ordl[r] = t;
  }
  __syncthreads();
  if (t < N_INST) {
    int o = ordl[t];
    order[t] = o;
    cls_sorted[t] = cls_idx[o];
    out_order[t] = (float)o;  // ints <= 99 exact in f32
  }
}

// K1: per-pixel softmax candidates. Softmax sums to 1 => at most 2 instances
// can have softmax >= 0.4. Track top-2 by raw logit (exp monotonic => exact),
// denominator summed with expf in np's sequential sorted-row order.
// Dense 4B winner record per pixel; 8B raw-value record only for candidates.
__global__ __launch_bounds__(256) void k1_cand(
    const float* __restrict__ mp,
    const int* __restrict__ order,
    unsigned int* __restrict__ masksum,
    unsigned int* __restrict__ paircnt,
    unsigned int* __restrict__ ab_rec,
    float2* __restrict__ rv_rec) {
  __shared__ int so[N_INST];
  if (threadIdx.x < N_INST) so[threadIdx.x] = order[threadIdx.x];
  __syncthreads();

  int p = blockIdx.x * 256 + threadIdx.x;

  float x[N_INST];
  // Pass 1: load + max + top-2 tracking on raw logits.
  float m1 = -3.0e38f, m2 = -3.0e38f;
  int s1 = 0, s2 = 0;
#pragma unroll
  for (int k = 0; k < N_INST; ++k) {
    float xv = mp[(size_t)so[k] * HW_PIX + p];
    x[k] = xv;
    if (xv > m1)      { m2 = m1; s2 = s1; m1 = xv; s1 = k; }
    else if (xv > m2) { m2 = xv; s2 = k; }
  }
  // Pass 2: denominator, sequential order 0..99 (matches np axis-0 reduce).
  float denom = 0.0f;
#pragma unroll
  for (int k = 0; k < N_INST; ++k) denom += expf(x[k] - m1);

  // e1 = expf(m1-m1) = expf(0) = 1 exactly (np identical).
  bool c1 = (1.0f / denom) >= 0.4f;
  bool c2 = (expf(m2 - m1) / denom) >= 0.4f;  // c2 implies c1

  unsigned int abv = 0xFFFFu;  // a=255,b=255 sentinel
  if (c1) {
    int a = s1, b = 255;
    float ra = m1, rb = 0.0f;
    atomicAdd(&masksum[s1], 1u);
    if (c2) {
      atomicAdd(&masksum[s2], 1u);
      if (s2 < s1) { a = s2; ra = m2; b = s1; rb = m1; }
      else         { b = s2; rb = m2; }
      atomicAdd(&paircnt[a * N_INST + b], 1u);
    }
    abv = (unsigned)a | ((unsigned)b << 8);
    rv_rec[p] = make_float2(ra, rb);  // divergent but rare
  }
  ab_rec[p] = abv;
}

// K2: sequential greedy keep, one block. overlap_s = sum over earlier kept
// same-class j of paircnt[j][s] (valid: a pixel has <=2 candidates, so
// mimg[c] at a pixel is set iff the pixel's other candidate was kept).
__global__ __launch_bounds__(256) void k2_keep(
    const unsigned int* __restrict__ paircnt,
    const unsigned int* __restrict__ masksum,
    const int* __restrict__ cls_sorted,
    unsigned long long* __restrict__ keepmask,
    float* __restrict__ out_keep) {
  __shared__ unsigned int pl[NPAIR];
  __shared__ unsigned int ms[N_INST];
  __shared__ int cl[N_INST];
  for (int i = threadIdx.x; i < NPAIR; i += 256) pl[i] = paircnt[i];
  if (threadIdx.x < N_INST) {
    ms[threadIdx.x] = masksum[threadIdx.x];
    cl[threadIdx.x] = cls_sorted[threadIdx.x];
  }
  __syncthreads();
  if (threadIdx.x < 64) {
    int l = threadIdx.x;
    int j2 = l + 64;
    int cA = cl[l];
    int cB = (j2 < N_INST) ? cl[j2] : -1;
    bool kA = false, kB = false;
    unsigned long long km0 = 0, km1 = 0;
    for (int s = 0; s < N_INST; ++s) {
      int cs = cl[s];
      unsigned int ov = 0;
      if (l < s && kA && cA == cs) ov += pl[l * N_INST + s];
      if (j2 < s && kB && cB == cs) ov += pl[j2 * N_INST + s];
#pragma unroll
      for (int off = 32; off >= 1; off >>= 1) ov += __shfl_xor((int)ov, off);
      unsigned int m_s = ms[s];
      float overlap = (float)ov / fmaxf((float)m_s, 1.0f);
      bool keep = (m_s > 0u) && (m_s < (unsigned)HW_PIX) && (overlap <= 0.03f);
      if (keep) { if (s < 64) km0 |= 1ull << s; else km1 |= 1ull << (s - 64); }
      if (s == l)  kA = keep;
      if (s == j2) kB = keep;
    }
    if (l == 0) { keepmask[0] = km0; keepmask[1] = km1; }
    out_keep[l] = kA ? 1.0f : 0.0f;
    if (j2 < N_INST) out_keep[j2] = kB ? 1.0f : 0.0f;
  }
}

// K3: full-write of kept_masks (replaces memset + scatter). 8 px/thread,
// dwordx4 stores (16 B/lane = 1 KB/wave). Zero everywhere except the winning
// candidate's raw value.
__global__ __launch_bounds__(256) void k3_write(
    const unsigned int* __restrict__ ab_rec,
    const float2* __restrict__ rv_rec,
    const unsigned long long* __restrict__ keepmask,
    float* __restrict__ out_masks) {
  unsigned long long km0 = keepmask[0], km1 = keepmask[1];
  int base = (blockIdx.x * 256 + threadIdx.x) * 8;
  int w[8];
  float val[8];
#pragma unroll
  for (int k = 0; k < 8; ++k) {
    unsigned int abv = ab_rec[base + k];
    int a = (int)(abv & 0xFF);
    int b = (int)((abv >> 8) & 0xFF);
    bool ka = (a < 64) ? (((km0 >> a) & 1ull) != 0)
                       : ((a < N_INST) && (((km1 >> (a - 64)) & 1ull) != 0));
    bool kb = (b < 64) ? (((km0 >> b) & 1ull) != 0)
                       : ((b < N_INST) && (((km1 >> (b - 64)) & 1ull) != 0));
    w[k] = ka ? a : (kb ? b : 255);
    if (w[k] != 255) {
      float2 rv = rv_rec[base + k];  // only valid (and needed) for candidates
      val[k] = ka ? rv.x : rv.y;
    } else {
      val[k] = 0.0f;
    }
  }
#pragma unroll 2
  for (int s = 0; s < N_INST; ++s) {
    float4 lo, hi;
    lo.x = (w[0] == s) ? val[0] : 0.0f;
    lo.y = (w[1] == s) ? val[1] : 0.0f;
    lo.z = (w[2] == s) ? val[2] : 0.0f;
    lo.w = (w[3] == s) ? val[3] : 0.0f;
    hi.x = (w[4] == s) ? val[4] : 0.0f;
    hi.y = (w[5] == s) ? val[5] : 0.0f;
    hi.z = (w[6] == s) ? val[6] : 0.0f;
    hi.w = (w[7] == s) ? val[7] : 0.0f;
    float* dst = out_masks + (size_t)s * HW_PIX + base;
    *(float4*)dst = lo;
    *(float4*)(dst + 4) = hi;
  }
}

extern "C" void kernel_launch(void* const* d_in, const int* in_sizes, int n_in,
                              void* d_out, int out_size, void* d_ws, size_t ws_size,
                              hipStream_t stream) {
  const float* cls_prob = (const float*)d_in[0];
  const float* mp       = (const float*)d_in[1];
  const int*   cls_idx  = (const int*)d_in[2];
  float* out = (float*)d_out;

  char* ws = (char*)d_ws;
  int* order                   = (int*)(ws + 0);       // 400 B
  int* cls_sorted              = (int*)(ws + 400);     // 400 B
  unsigned long long* keepmask = (unsigned long long*)(ws + 800);  // 16 B
  unsigned int* masksum        = (unsigned int*)(ws + 1024);       // 400 B
  unsigned int* paircnt        = (unsigned int*)(ws + 2048);       // 40 KB
  unsigned int* ab_rec         = (unsigned int*)(ws + 65536);      // 3.28 MB
  float2* rv_rec               = (float2*)(ws + 65536 + 4 * HW_PIX);  // 6.55 MB

  // output layout (f32): keep[100] | kept_masks[100*HW] | order[100]
  float* out_keep  = out;
  float* out_masks = out + N_INST;
  float* out_order = out + N_INST + (size_t)N_INST * HW_PIX;

  // Zero only the tiny accumulators (ws is poisoned 0xAA each launch).
  hipMemsetAsync(ws + 1024, 0, 1024 + 40000, stream);

  k0_sort<<<1, 128, 0, stream>>>(cls_prob, cls_idx, order, cls_sorted, out_order);
  k1_cand<<<HW_PIX / 256, 256, 0, stream>>>(mp, order, masksum, paircnt, ab_rec, rv_rec);
  k2_keep<<<1, 256, 0, stream>>>(paircnt, masksum, cls_sorted, keepmask, out_keep);
  k3_write<<<HW_PIX / (256 * 8), 256, 0, stream>>>(ab_rec, rv_rec, keepmask, out_masks);
}

// Round 4
// 753.616 us; speedup vs baseline: 1.1806x; 1.1806x over previous
//
#include <hip/hip_runtime.h>

#define N_INST 100
#define HW_PIX 819200
#define NPAIR (N_INST * N_INST)

// K0: argsort(cls_prob) descending, tie-break larger original index first
// (== jnp stable-ascending argsort reversed). Also zeroes the k1 accumulators
// (masksum+paircnt) so no separate memset dispatch is needed.
__global__ __launch_bounds__(256) void k0_sort(
    const float* __restrict__ cls_prob,
    const int* __restrict__ cls_idx,
    int* __restrict__ order,
    int* __restrict__ cls_sorted,
    float* __restrict__ out_order,
    unsigned int* __restrict__ masksum,
    unsigned int* __restrict__ paircnt) {
  __shared__ float v[N_INST];
  __shared__ int ordl[N_INST];
  int t = threadIdx.x;
  // zero accumulators (ws is poisoned 0xAA each launch)
  for (int i = t; i < N_INST; i += 256) masksum[i] = 0u;
  for (int i = t; i < NPAIR; i += 256) paircnt[i] = 0u;
  if (t < N_INST) v[t] = cls_prob[t];
  __syncthreads();
  if (t < N_INST) {
    float mv = v[t];
    int r = 0;
    for (int j = 0; j < N_INST; ++j) {
      float vj = v[j];
      r += (vj > mv) || (vj == mv && j > t);
    }
    ordl[r] = t;
  }
  __syncthreads();
  if (t < N_INST) {
    int o = ordl[t];
    order[t] = o;
    cls_sorted[t] = cls_idx[o];
    out_order[t] = (float)o;  // ints <= 99 exact in f32
  }
}

// K1: per-pixel softmax candidates. Softmax sums to 1 => at most 2 instances
// can have softmax >= 0.4. Track top-2 by raw logit (exp monotonic => exact),
// denominator summed with precise expf in np's sequential sorted-row order.
// __launch_bounds__(256,3): ~170 VGPR budget so x[100] stays in registers
// (round-3 evidence: default bounds gave VGPR_Count=60 -> full scratch spill,
// 254us @ 656 GB/s).
__global__ __launch_bounds__(256, 3) void k1_cand(
    const float* __restrict__ mp,
    const int* __restrict__ order,
    unsigned int* __restrict__ masksum,
    unsigned int* __restrict__ paircnt,
    unsigned int* __restrict__ ab_rec,
    float2* __restrict__ rv_rec) {
  __shared__ int so[N_INST];
  if (threadIdx.x < N_INST) so[threadIdx.x] = order[threadIdx.x];
  __syncthreads();

  int p = blockIdx.x * 256 + threadIdx.x;
  const float* col = mp + p;

  // Load-only loop: 100 independent global loads in flight.
  float x[N_INST];
#pragma unroll
  for (int k = 0; k < N_INST; ++k)
    x[k] = col[(size_t)so[k] * HW_PIX];

  // Max + top-2 on raw logits (exp is monotonic, so identical selection).
  float m1 = -3.0e38f, m2 = -3.0e38f;
  int s1 = 0, s2 = 0;
#pragma unroll
  for (int k = 0; k < N_INST; ++k) {
    float xv = x[k];
    if (xv > m1)      { m2 = m1; s2 = s1; m1 = xv; s1 = k; }
    else if (xv > m2) { m2 = xv; s2 = k; }
  }

  // Denominator: sequential order 0..99, precise expf (np-exact; absmax==0
  // in rounds 2-3 confirms bit-match).
  float denom = 0.0f;
#pragma unroll
  for (int k = 0; k < N_INST; ++k) denom += expf(x[k] - m1);

  // e1 = expf(0) = 1 exactly.
  bool c1 = (1.0f / denom) >= 0.4f;
  bool c2 = (expf(m2 - m1) / denom) >= 0.4f;  // c2 implies c1

  unsigned int abv = 0xFFFFu;  // a=255,b=255 sentinel
  if (c1) {
    int a = s1, b = 255;
    float ra = m1, rb = 0.0f;
    atomicAdd(&masksum[s1], 1u);
    if (c2) {
      atomicAdd(&masksum[s2], 1u);
      if (s2 < s1) { a = s2; ra = m2; b = s1; rb = m1; }
      else         { b = s2; rb = m2; }
      atomicAdd(&paircnt[a * N_INST + b], 1u);
    }
    abv = (unsigned)a | ((unsigned)b << 8);
    rv_rec[p] = make_float2(ra, rb);  // divergent but rare
  }
  ab_rec[p] = abv;
}

// K2: sequential greedy keep, one block. overlap_s = sum over earlier kept
// same-class j of paircnt[j][s] (valid: a pixel has <=2 candidates, so
// mimg[c] at a pixel is set iff the pixel's other candidate was kept).
__global__ __launch_bounds__(256) void k2_keep(
    const unsigned int* __restrict__ paircnt,
    const unsigned int* __restrict__ masksum,
    const int* __restrict__ cls_sorted,
    unsigned long long* __restrict__ keepmask,
    float* __restrict__ out_keep) {
  __shared__ unsigned int pl[NPAIR];
  __shared__ unsigned int ms[N_INST];
  __shared__ int cl[N_INST];
  for (int i = threadIdx.x; i < NPAIR; i += 256) pl[i] = paircnt[i];
  if (threadIdx.x < N_INST) {
    ms[threadIdx.x] = masksum[threadIdx.x];
    cl[threadIdx.x] = cls_sorted[threadIdx.x];
  }
  __syncthreads();
  if (threadIdx.x < 64) {
    int l = threadIdx.x;
    int j2 = l + 64;
    int cA = cl[l];
    int cB = (j2 < N_INST) ? cl[j2] : -1;
    bool kA = false, kB = false;
    unsigned long long km0 = 0, km1 = 0;
    for (int s = 0; s < N_INST; ++s) {
      int cs = cl[s];
      unsigned int ov = 0;
      if (l < s && kA && cA == cs) ov += pl[l * N_INST + s];
      if (j2 < s && kB && cB == cs) ov += pl[j2 * N_INST + s];
#pragma unroll
      for (int off = 32; off >= 1; off >>= 1) ov += __shfl_xor((int)ov, off);
      unsigned int m_s = ms[s];
      float overlap = (float)ov / fmaxf((float)m_s, 1.0f);
      bool keep = (m_s > 0u) && (m_s < (unsigned)HW_PIX) && (overlap <= 0.03f);
      if (keep) { if (s < 64) km0 |= 1ull << s; else km1 |= 1ull << (s - 64); }
      if (s == l)  kA = keep;
      if (s == j2) kB = keep;
    }
    if (l == 0) { keepmask[0] = km0; keepmask[1] = km1; }
    out_keep[l] = kA ? 1.0f : 0.0f;
    if (j2 < N_INST) out_keep[j2] = kB ? 1.0f : 0.0f;
  }
}

// K3: full-write of kept_masks (doubles as the zero-fill of the poisoned
// output). 8 px/thread, two dwordx4 stores per instance row.
__global__ __launch_bounds__(256) void k3_write(
    const unsigned int* __restrict__ ab_rec,
    const float2* __restrict__ rv_rec,
    const unsigned long long* __restrict__ keepmask,
    float* __restrict__ out_masks) {
  unsigned long long km0 = keepmask[0], km1 = keepmask[1];
  int base = (blockIdx.x * 256 + threadIdx.x) * 8;
  int w[8];
  float val[8];
#pragma unroll
  for (int k = 0; k < 8; ++k) {
    unsigned int abv = ab_rec[base + k];
    int a = (int)(abv & 0xFF);
    int b = (int)((abv >> 8) & 0xFF);
    bool ka = (a < 64) ? (((km0 >> a) & 1ull) != 0)
                       : ((a < N_INST) && (((km1 >> (a - 64)) & 1ull) != 0));
    bool kb = (b < 64) ? (((km0 >> b) & 1ull) != 0)
                       : ((b < N_INST) && (((km1 >> (b - 64)) & 1ull) != 0));
    w[k] = ka ? a : (kb ? b : 255);
    if (w[k] != 255) {
      float2 rv = rv_rec[base + k];  // only valid (and needed) for candidates
      val[k] = ka ? rv.x : rv.y;
    } else {
      val[k] = 0.0f;
    }
  }
#pragma unroll 2
  for (int s = 0; s < N_INST; ++s) {
    float4 lo, hi;
    lo.x = (w[0] == s) ? val[0] : 0.0f;
    lo.y = (w[1] == s) ? val[1] : 0.0f;
    lo.z = (w[2] == s) ? val[2] : 0.0f;
    lo.w = (w[3] == s) ? val[3] : 0.0f;
    hi.x = (w[4] == s) ? val[4] : 0.0f;
    hi.y = (w[5] == s) ? val[5] : 0.0f;
    hi.z = (w[6] == s) ? val[6] : 0.0f;
    hi.w = (w[7] == s) ? val[7] : 0.0f;
    float* dst = out_masks + (size_t)s * HW_PIX + base;
    *(float4*)dst = lo;
    *(float4*)(dst + 4) = hi;
  }
}

extern "C" void kernel_launch(void* const* d_in, const int* in_sizes, int n_in,
                              void* d_out, int out_size, void* d_ws, size_t ws_size,
                              hipStream_t stream) {
  const float* cls_prob = (const float*)d_in[0];
  const float* mp       = (const float*)d_in[1];
  const int*   cls_idx  = (const int*)d_in[2];
  float* out = (float*)d_out;

  char* ws = (char*)d_ws;
  int* order                   = (int*)(ws + 0);       // 400 B
  int* cls_sorted              = (int*)(ws + 400);     // 400 B
  unsigned long long* keepmask = (unsigned long long*)(ws + 800);  // 16 B
  unsigned int* masksum        = (unsigned int*)(ws + 1024);       // 400 B
  unsigned int* paircnt        = (unsigned int*)(ws + 2048);       // 40 KB
  unsigned int* ab_rec         = (unsigned int*)(ws + 65536);      // 3.28 MB
  float2* rv_rec               = (float2*)(ws + 65536 + 4 * HW_PIX);  // 6.55 MB

  // output layout (f32): keep[100] | kept_masks[100*HW] | order[100]
  float* out_keep  = out;
  float* out_masks = out + N_INST;
  float* out_order = out + N_INST + (size_t)N_INST * HW_PIX;

  k0_sort<<<1, 256, 0, stream>>>(cls_prob, cls_idx, order, cls_sorted, out_order,
                                 masksum, paircnt);
  k1_cand<<<HW_PIX / 256, 256, 0, stream>>>(mp, order, masksum, paircnt, ab_rec, rv_rec);
  k2_keep<<<1, 256, 0, stream>>>(paircnt, masksum, cls_sorted, keepmask, out_keep);
  k3_write<<<HW_PIX / (256 * 8), 256, 0, stream>>>(ab_rec, rv_rec, keepmask, out_masks);
}